// Round 2
// baseline (142.596 us; speedup 1.0000x reference)
//
#include <hip/hip_runtime.h>
#include <math.h>

#define DDIM 512
#define BDIM 256
#define NCLS 85742
#define NB_COL 1024
#define CHUNK ((NCLS + NB_COL - 1) / NB_COL)   // 84 rows per block

__device__ __forceinline__ float wave_reduce(float v) {
    #pragma unroll
    for (int off = 32; off > 0; off >>= 1)
        v += __shfl_down(v, off, 64);
    return v;
}

__device__ __forceinline__ float block_reduce(float v, float* smem) {
    const int lane = threadIdx.x & 63;
    const int wid  = threadIdx.x >> 6;
    v = wave_reduce(v);
    if (lane == 0) smem[wid] = v;
    __syncthreads();
    if (wid == 0) {
        v = (lane < (int)(blockDim.x >> 6)) ? smem[lane] : 0.0f;
        v = wave_reduce(v);
    }
    return v;
}

// K1: colsum[d] = sum_c W[c][d].
// 256 threads: thread t owns float4 column col4 = t&127, row-parity rsub = t>>7.
// Each block owns a contiguous CHUNK of rows; 8 independent float4 loads in
// flight per thread (unrolled pairs) for latency hiding.
__global__ void colsum_kernel(const float* __restrict__ W,
                              float* __restrict__ colsum) {
    const int t = threadIdx.x;
    const int col4 = t & 127;
    const int rsub = t >> 7;                       // 0 or 1
    const float4* __restrict__ W4 = reinterpret_cast<const float4*>(W);

    const int r0 = blockIdx.x * CHUNK;
    if (r0 >= NCLS) return;                        // block-uniform
    const int r1 = (r0 + CHUNK < NCLS) ? r0 + CHUNK : NCLS;

    float4 acc = make_float4(0.f, 0.f, 0.f, 0.f);
    int r = r0 + rsub;
    for (; r + 14 < r1; r += 16) {
        float4 v0 = W4[(size_t)(r     ) * 128 + col4];
        float4 v1 = W4[(size_t)(r +  2) * 128 + col4];
        float4 v2 = W4[(size_t)(r +  4) * 128 + col4];
        float4 v3 = W4[(size_t)(r +  6) * 128 + col4];
        float4 v4 = W4[(size_t)(r +  8) * 128 + col4];
        float4 v5 = W4[(size_t)(r + 10) * 128 + col4];
        float4 v6 = W4[(size_t)(r + 12) * 128 + col4];
        float4 v7 = W4[(size_t)(r + 14) * 128 + col4];
        acc.x += ((v0.x + v1.x) + (v2.x + v3.x)) + ((v4.x + v5.x) + (v6.x + v7.x));
        acc.y += ((v0.y + v1.y) + (v2.y + v3.y)) + ((v4.y + v5.y) + (v6.y + v7.y));
        acc.z += ((v0.z + v1.z) + (v2.z + v3.z)) + ((v4.z + v5.z) + (v6.z + v7.z));
        acc.w += ((v0.w + v1.w) + (v2.w + v3.w)) + ((v4.w + v5.w) + (v6.w + v7.w));
    }
    for (; r < r1; r += 2) {
        float4 v = W4[(size_t)r * 128 + col4];
        acc.x += v.x; acc.y += v.y; acc.z += v.z; acc.w += v.w;
    }

    __shared__ float4 smem[128];
    if (rsub) smem[col4] = acc;
    __syncthreads();
    if (!rsub) {
        float4 o = smem[col4];
        atomicAdd(&colsum[col4 * 4 + 0], acc.x + o.x);
        atomicAdd(&colsum[col4 * 4 + 1], acc.y + o.y);
        atomicAdd(&colsum[col4 * 4 + 2], acc.z + o.z);
        atomicAdd(&colsum[col4 * 4 + 3], acc.w + o.w);
    }
}

// K2: Sy = sum (wy-mu)^2 ; Si = sum (colsum - wy - mu)^2   over B*D elements
__global__ void dist_kernel(const float* __restrict__ mu,
                            const float* __restrict__ W,
                            const int*   __restrict__ label,
                            const float* __restrict__ colsum,
                            float* __restrict__ sums) {
    __shared__ float smem[8];
    float dy2 = 0.0f, di2 = 0.0f;
    const int n = BDIM * DDIM;
    for (int i = blockIdx.x * blockDim.x + threadIdx.x; i < n;
         i += gridDim.x * blockDim.x) {
        const int b = i >> 9;        // i / 512
        const int d = i & 511;       // i % 512
        const float w = W[(size_t)label[b] * DDIM + d];
        const float m = mu[i];
        const float a = w - m;
        dy2 += a * a;
        const float c = colsum[d] - w - m;
        di2 += c * c;
    }
    dy2 = block_reduce(dy2, smem);
    __syncthreads();
    di2 = block_reduce(di2, smem);
    if (threadIdx.x == 0) {
        atomicAdd(&sums[0], dy2);
        atomicAdd(&sums[1], di2);
    }
}

// K3: loss = sum erf(dy/(sqrt2*std)) + erfc(di/(sqrt2*std))
__global__ void loss_kernel(const float* __restrict__ stdv,
                            const float* __restrict__ sums,
                            float* __restrict__ out) {
    __shared__ float smem[8];
    const float dy = sqrtf(sums[0]);
    const float di = sqrtf(sums[1]);
    const float inv_sqrt2 = 0.70710678118654752f;
    float acc = 0.0f;
    const int n = BDIM * DDIM;
    for (int i = blockIdx.x * blockDim.x + threadIdx.x; i < n;
         i += gridDim.x * blockDim.x) {
        const float s = stdv[i];
        const float r = inv_sqrt2 / s;
        acc += erff(dy * r) + erfcf(di * r);
    }
    acc = block_reduce(acc, smem);
    if (threadIdx.x == 0) atomicAdd(out, acc);
}

extern "C" void kernel_launch(void* const* d_in, const int* in_sizes, int n_in,
                              void* d_out, int out_size, void* d_ws, size_t ws_size,
                              hipStream_t stream) {
    // inputs: 0=x (unused), 1=mu, 2=std, 3=weight, 4=label
    const float* mu    = (const float*)d_in[1];
    const float* stdv  = (const float*)d_in[2];
    const float* W     = (const float*)d_in[3];
    const int*   label = (const int*)d_in[4];
    float* out = (float*)d_out;
    float* ws  = (float*)d_ws;   // ws[0..511]=colsum, ws[512]=Sy, ws[513]=Si

    hipMemsetAsync(d_ws, 0, (DDIM + 2) * sizeof(float), stream);
    hipMemsetAsync(d_out, 0, sizeof(float), stream);

    colsum_kernel<<<NB_COL, 256, 0, stream>>>(W, ws);
    dist_kernel<<<256, 256, 0, stream>>>(mu, W, label, ws, ws + DDIM);
    loss_kernel<<<256, 256, 0, stream>>>(stdv, ws + DDIM, out);
}